// Round 2
// baseline (17602.917 us; speedup 1.0000x reference)
//
#include <hip/hip_runtime.h>

#define BSZ 512
#define LSEQ 128
#define HH 512
#define AA 128
#define NC 640    // H + A
#define N1 1152   // H + NC
#define KD 512
#define SBR 16    // batch rows per scan block

typedef short s8v __attribute__((ext_vector_type(8)));
typedef float f4v __attribute__((ext_vector_type(4)));

__device__ __forceinline__ unsigned short bf16_rne(float f) {
  unsigned int u = __float_as_uint(f);
  u += 0x7fffu + ((u >> 16) & 1u);
  return (unsigned short)(u >> 16);
}
__device__ __forceinline__ float bf16_tof(unsigned short s) {
  return __uint_as_float(((unsigned int)s) << 16);
}
__device__ __forceinline__ float fast_tanh(float x) {
  float t = __expf(2.f * x);      // inf-safe: x>>0 -> 1, x<<0 -> -1
  return 1.f - 2.f / (t + 1.f);
}

// ---------------- prep kernels ----------------

__global__ __launch_bounds__(256) void concat_k(
    const float* __restrict__ U, const float* __restrict__ Ua1,
    const float* __restrict__ W, const float* __restrict__ Wa1,
    const float* __restrict__ bb, const float* __restrict__ ba1,
    float* __restrict__ Ucat, float* __restrict__ Wcat, float* __restrict__ bias2)
{
  int idx = blockIdx.x * 256 + threadIdx.x;
  if (idx < KD * NC) {
    int k = idx / NC, c = idx % NC;
    Ucat[idx] = (c < HH) ? U[k * HH + c] : Ua1[k * AA + (c - HH)];
    Wcat[idx] = (c < HH) ? W[k * HH + c] : Wa1[k * AA + (c - HH)];
  }
  if (idx < NC) bias2[idx] = (idx < HH) ? bb[idx] : ba1[idx - HH];
}

// Wcomb = W_emb @ Wcat  (exact f32)
__global__ __launch_bounds__(NC) void comb_k(
    const float* __restrict__ Wemb, const float* __restrict__ Wcat,
    float* __restrict__ Wcomb)
{
  __shared__ float arow[KD];
  int m = blockIdx.x, n = threadIdx.x;
  for (int i = threadIdx.x; i < KD; i += NC) arow[i] = Wemb[m * HH + i];
  __syncthreads();
  float a0 = 0.f, a1 = 0.f, a2 = 0.f, a3 = 0.f;
  for (int k = 0; k < KD; k += 4) {
    a0 = fmaf(arow[k],     Wcat[(size_t)(k)     * NC + n], a0);
    a1 = fmaf(arow[k + 1], Wcat[(size_t)(k + 1) * NC + n], a1);
    a2 = fmaf(arow[k + 2], Wcat[(size_t)(k + 2) * NC + n], a2);
    a3 = fmaf(arow[k + 3], Wcat[(size_t)(k + 3) * NC + n], a3);
  }
  Wcomb[(size_t)m * NC + n] = (a0 + a1) + (a2 + a3);
}

// bias1 = [b_emb | b_emb @ Wcat + bias2]
__global__ __launch_bounds__(NC) void bcomb_k(
    const float* __restrict__ bemb, const float* __restrict__ Wcat,
    const float* __restrict__ bias2, float* __restrict__ bias1)
{
  __shared__ float be[KD];
  int n = threadIdx.x;
  for (int i = n; i < KD; i += NC) be[i] = bemb[i];
  __syncthreads();
  float acc = 0.f;
  for (int k = 0; k < KD; ++k) acc = fmaf(be[k], Wcat[(size_t)k * NC + n], acc);
  bias1[HH + n] = acc + bias2[n];
  if (n < HH) bias1[n] = bemb[n];
}

// transpose + split f32 [KD][N] -> bf16 hi/lo [N][KD]
__global__ __launch_bounds__(256) void tsplit_k(
    const float* __restrict__ src, int N,
    unsigned short* __restrict__ dsth, unsigned short* __restrict__ dstl, int row_off)
{
  __shared__ float tile[32][33];
  int k0 = blockIdx.x * 32, n0 = blockIdx.y * 32;
  int tx = threadIdx.x & 31, ty = threadIdx.x >> 5;
  for (int i = ty; i < 32; i += 8) {
    int n = n0 + tx;
    tile[i][tx] = (n < N) ? src[(size_t)(k0 + i) * N + n] : 0.f;
  }
  __syncthreads();
  for (int i = ty; i < 32; i += 8) {
    int n = n0 + i;
    if (n >= N) continue;
    float v = tile[tx][i];
    unsigned short h = bf16_rne(v);
    unsigned short l = bf16_rne(v - bf16_tof(h));
    dsth[(size_t)(row_off + n) * KD + k0 + tx] = h;
    dstl[(size_t)(row_off + n) * KD + k0 + tx] = l;
  }
}

// ---------------- split-bf16 3-term MFMA GEMM ----------------
// AMODE 0: A = f32 x with chunk row remap arow=(m&511)*128+c0+(m>>9)
// AMODE 1: A = packed bf16-pair u32 [M][512] (hi<<16|lo), dense rows
// OMODE 1: n<512 -> packed pair to o_xe[m*512+n]; n>=512 -> o_xp[m*640+n-512]
// OMODE 2: o_xp[m*640+n]
template<int AMODE, int OMODE>
__global__ __launch_bounds__(256, 2) void gemm_k(
    const float* __restrict__ Af, const unsigned int* __restrict__ Ap,
    const unsigned short* __restrict__ BTh, const unsigned short* __restrict__ BTl,
    const float* __restrict__ bias, int NT, int c0,
    unsigned int* __restrict__ o_xe, float* __restrict__ o_xp)
{
  __shared__ __align__(16) unsigned short As_h[128][72];
  __shared__ __align__(16) unsigned short As_l[128][72];
  __shared__ __align__(16) unsigned short Bs_h[128][72];
  __shared__ __align__(16) unsigned short Bs_l[128][72];
  const int tid = threadIdx.x;
  const int lane = tid & 63, w = tid >> 6;
  const int wm = w >> 1, wn = w & 1;
  const int m0 = (blockIdx.x / NT) * 128, n0 = (blockIdx.x % NT) * 128;

  f4v acc[4][4];
#pragma unroll
  for (int i = 0; i < 4; ++i)
#pragma unroll
    for (int j = 0; j < 4; ++j) acc[i][j] = (f4v){0.f, 0.f, 0.f, 0.f};

  for (int kt = 0; kt < KD; kt += 64) {
    __syncthreads();
    if (AMODE == 0) {
#pragma unroll
      for (int p = 0; p < 8; ++p) {
        int li = tid + p * 256;
        int row = li >> 4, kc = (li & 15) << 2;
        int m = m0 + row;
        int arow = (m & 511) * 128 + c0 + (m >> 9);
        const float4 v = *(const float4*)&Af[(size_t)arow * KD + kt + kc];
        unsigned short h0 = bf16_rne(v.x), h1 = bf16_rne(v.y), h2 = bf16_rne(v.z), h3 = bf16_rne(v.w);
        unsigned short l0 = bf16_rne(v.x - bf16_tof(h0));
        unsigned short l1 = bf16_rne(v.y - bf16_tof(h1));
        unsigned short l2 = bf16_rne(v.z - bf16_tof(h2));
        unsigned short l3 = bf16_rne(v.w - bf16_tof(h3));
        *(ushort4*)&As_h[row][kc] = make_ushort4(h0, h1, h2, h3);
        *(ushort4*)&As_l[row][kc] = make_ushort4(l0, l1, l2, l3);
      }
    } else {
#pragma unroll
      for (int p = 0; p < 4; ++p) {
        int li = tid + p * 256;
        int row = li >> 3, kc = (li & 7) << 3;
        const uint4 a = *(const uint4*)&Ap[(size_t)(m0 + row) * KD + kt + kc];
        const uint4 b = *(const uint4*)&Ap[(size_t)(m0 + row) * KD + kt + kc + 4];
        s8v hv, lv;
        hv[0] = (short)(a.x >> 16); lv[0] = (short)(a.x & 0xffff);
        hv[1] = (short)(a.y >> 16); lv[1] = (short)(a.y & 0xffff);
        hv[2] = (short)(a.z >> 16); lv[2] = (short)(a.z & 0xffff);
        hv[3] = (short)(a.w >> 16); lv[3] = (short)(a.w & 0xffff);
        hv[4] = (short)(b.x >> 16); lv[4] = (short)(b.x & 0xffff);
        hv[5] = (short)(b.y >> 16); lv[5] = (short)(b.y & 0xffff);
        hv[6] = (short)(b.z >> 16); lv[6] = (short)(b.z & 0xffff);
        hv[7] = (short)(b.w >> 16); lv[7] = (short)(b.w & 0xffff);
        *(s8v*)&As_h[row][kc] = hv;
        *(s8v*)&As_l[row][kc] = lv;
      }
    }
#pragma unroll
    for (int p = 0; p < 4; ++p) {
      int li = tid + p * 256;
      int row = li >> 3, kc = (li & 7) << 3;
      *(s8v*)&Bs_h[row][kc] = *(const s8v*)&BTh[(size_t)(n0 + row) * KD + kt + kc];
      *(s8v*)&Bs_l[row][kc] = *(const s8v*)&BTl[(size_t)(n0 + row) * KD + kt + kc];
    }
    __syncthreads();
#pragma unroll
    for (int kk = 0; kk < 2; ++kk) {
      const int kb = kk * 32 + (lane >> 4) * 8;
      s8v ah[4], alo[4], bh[4], blo[4];
#pragma unroll
      for (int i = 0; i < 4; ++i) {
        int ra = wm * 64 + i * 16 + (lane & 15);
        int rb = wn * 64 + i * 16 + (lane & 15);
        ah[i]  = *(const s8v*)&As_h[ra][kb];
        alo[i] = *(const s8v*)&As_l[ra][kb];
        bh[i]  = *(const s8v*)&Bs_h[rb][kb];
        blo[i] = *(const s8v*)&Bs_l[rb][kb];
      }
#pragma unroll
      for (int mi = 0; mi < 4; ++mi)
#pragma unroll
        for (int ni = 0; ni < 4; ++ni) {
          acc[mi][ni] = __builtin_amdgcn_mfma_f32_16x16x32_bf16(alo[mi], bh[ni], acc[mi][ni], 0, 0, 0);
          acc[mi][ni] = __builtin_amdgcn_mfma_f32_16x16x32_bf16(ah[mi], blo[ni], acc[mi][ni], 0, 0, 0);
          acc[mi][ni] = __builtin_amdgcn_mfma_f32_16x16x32_bf16(ah[mi], bh[ni], acc[mi][ni], 0, 0, 0);
        }
    }
  }
#pragma unroll
  for (int mi = 0; mi < 4; ++mi) {
#pragma unroll
    for (int ni = 0; ni < 4; ++ni) {
      int n = n0 + wn * 64 + ni * 16 + (lane & 15);
      float bv = bias[n];
#pragma unroll
      for (int r = 0; r < 4; ++r) {
        int m = m0 + wm * 64 + mi * 16 + (lane >> 4) * 4 + r;
        float val = acc[mi][ni][r] + bv;
        if (OMODE == 1) {
          if (n < HH) {
            unsigned short hb = bf16_rne(val);
            unsigned short lb = bf16_rne(val - bf16_tof(hb));
            o_xe[(size_t)m * KD + n] = ((unsigned int)hb << 16) | lb;
          } else {
            o_xp[(size_t)m * NC + (n - HH)] = val;
          }
        } else {
          o_xp[(size_t)m * NC + n] = val;
        }
      }
    }
  }
}

// ---------------- MFMA sequential scan (one layer, one chunk) ----------------
// 32 blocks x 512 threads; block owns 16 batch rows. Per step:
// Y[16][640] = h[16][512] @ Ucat (3-term split-bf16 MFMA, B from global UT),
// pol/hnew from XP+Y, logits, gating, h update. State persists via hstate.
__global__ __launch_bounds__(512) void scan2_k(
    const unsigned int* __restrict__ xin,   // packed pair, chunk [CH*512][512]
    const float* __restrict__ XPc,          // [CH*512][640]
    const unsigned short* __restrict__ UTh, const unsigned short* __restrict__ UTl, // [640][512]
    const float* __restrict__ Wa2, const float* __restrict__ ba2,
    const int* __restrict__ mask,           // [512][128]
    const int* __restrict__ acts_in, const int* __restrict__ ndms_in, // full [128][512] or null
    int* __restrict__ acts_out, int* __restrict__ ndms_out,
    unsigned int* __restrict__ hout,        // packed chunk or null
    unsigned int* __restrict__ hstate,      // packed [512][512]
    int* __restrict__ aTbuf, int* __restrict__ dTbuf,
    float* __restrict__ dout, int LL, int c0, int CH, int FIRST)
{
  __shared__ __align__(16) unsigned short hh[SBR][520];
  __shared__ __align__(16) unsigned short hl[SBR][520];
  __shared__ float ya[SBR][NC];
  __shared__ float hnew[SBR][HH];
  __shared__ float pol[SBR][AA];
  __shared__ float sWa2[AA * 2];
  __shared__ float sba2[2];
  __shared__ float lg[SBR][2];
  __shared__ int gB[SBR], gH[SBR], gX[SBR], gDP[SBR], sAT[SBR], sDT[SBR];

  const int tid = threadIdx.x;
  const int lane = tid & 63, w = tid >> 6;
  const int b0 = blockIdx.x * SBR;
  const int ar = lane & 15, g = lane >> 4;

  if (tid < AA * 2) sWa2[tid] = Wa2[tid];
  if (tid < 2) sba2[tid] = ba2[tid];
  if (tid < SBR) {
    sAT[tid] = FIRST ? 0 : aTbuf[b0 + tid];
    sDT[tid] = FIRST ? 0 : dTbuf[b0 + tid];
  }
#pragma unroll
  for (int r = 0; r < SBR; ++r) {
    unsigned int u = FIRST ? 0u : hstate[(size_t)(b0 + r) * KD + tid];
    hh[r][tid] = (unsigned short)(u >> 16);
    hl[r][tid] = (unsigned short)(u & 0xffff);
  }
  __syncthreads();

  for (int tl = 0; tl < CH; ++tl) {
    // ---- phase A: Y = h @ Ucat via MFMA ----
    f4v acc[5];
#pragma unroll
    for (int nt = 0; nt < 5; ++nt) acc[nt] = (f4v){0.f, 0.f, 0.f, 0.f};
#pragma unroll 4
    for (int ks = 0; ks < 16; ++ks) {
      const int ko = ks * 32 + g * 8;
      s8v ah = *(const s8v*)&hh[ar][ko];
      s8v al = *(const s8v*)&hl[ar][ko];
#pragma unroll
      for (int nt = 0; nt < 5; ++nt) {
        const size_t boff = (size_t)(w * 80 + nt * 16 + ar) * KD + ko;
        s8v bh = *(const s8v*)&UTh[boff];
        s8v bl = *(const s8v*)&UTl[boff];
        acc[nt] = __builtin_amdgcn_mfma_f32_16x16x32_bf16(al, bh, acc[nt], 0, 0, 0);
        acc[nt] = __builtin_amdgcn_mfma_f32_16x16x32_bf16(ah, bl, acc[nt], 0, 0, 0);
        acc[nt] = __builtin_amdgcn_mfma_f32_16x16x32_bf16(ah, bh, acc[nt], 0, 0, 0);
      }
    }
#pragma unroll
    for (int nt = 0; nt < 5; ++nt)
#pragma unroll
      for (int r = 0; r < 4; ++r)
        ya[g * 4 + r][w * 80 + nt * 16 + ar] = acc[nt][r];
    __syncthreads();

    // ---- phase B: hnew = tanh(XPw + yw), pol = relu(XPa + ya) ----
    {
      const size_t xpbase = ((size_t)tl * BSZ + b0) * NC;
#pragma unroll 4
      for (int r = 0; r < SBR; ++r)
        hnew[r][tid] = fast_tanh(XPc[xpbase + (size_t)r * NC + tid] + ya[r][tid]);
      const int cola = tid & 127, rb = tid >> 7;
#pragma unroll
      for (int q = 0; q < 4; ++q) {
        int r = q * 4 + rb;
        float v = XPc[xpbase + (size_t)r * NC + HH + cola] + ya[r][HH + cola];
        pol[r][cola] = fmaxf(v, 0.f);
      }
    }
    __syncthreads();

    // ---- phase C: logits ----
    {
      int g16 = lane >> 4, li = lane & 15;
      int r = 2 * w + (g16 >> 1), j = g16 & 1;
      float p = 0.f;
#pragma unroll
      for (int i = 0; i < 8; ++i)
        p = fmaf(pol[r][li + 16 * i], sWa2[(li + 16 * i) * 2 + j], p);
      p += __shfl_xor(p, 1); p += __shfl_xor(p, 2);
      p += __shfl_xor(p, 4); p += __shfl_xor(p, 8);
      if (li == 0) lg[r][j] = p + sba2[j];
    }
    __syncthreads();

    // ---- phase D: gating state machine ----
    if (tid < SBR) {
      int r = tid, b = b0 + r, t = c0 + tl;
      int A  = (acts_in && t < LSEQ - 1) ? acts_in[(t + 1) * BSZ + b] : 0;
      int DP = ndms_in ? ndms_in[t * BSZ + b] : mask[b * LSEQ + t];
      int mt = mask[b * LSEQ + t];
      int mt1 = (t < LSEQ - 1) ? mask[b * LSEQ + t + 1] : 0;
      int E = mt * (1 - mt1);
      int act = (lg[r][0] >= lg[r][1]) ? 1 : 0;
      if (A > 0) act = 1;
      if (LL) act = 1;
      if (E > 0) act = 0;
      int DT = sDT[r];
      int both  = (1 - A) * DP * act * DT;
      int honly = DT * act * (A + (1 - A) * (1 - DP));
      int xonly = DP * (1 - A) * (1 - act + act * (1 - DT));
      int ndm = DP * (both + xonly + honly);
      int aout = DP ? act : sAT[r];
      gB[r] = both; gH[r] = honly; gX[r] = xonly; gDP[r] = DP;
      sAT[r] = aout; sDT[r] = ndm;
      if (acts_out) acts_out[t * BSZ + b] = aout;
      if (ndms_out) ndms_out[t * BSZ + b] = ndm;
    }
    __syncthreads();

    // ---- phase E: h update + outputs ----
#pragma unroll 4
    for (int r = 0; r < SBR; ++r) {
      float vold = bf16_tof(hh[r][tid]) + bf16_tof(hl[r][tid]);
      float v;
      if (gB[r]) v = hnew[r][tid];
      else if (gH[r]) v = vold;
      else if (gX[r]) {
        unsigned int u = xin[((size_t)tl * BSZ + b0 + r) * KD + tid];
        v = bf16_tof((unsigned short)(u >> 16)) + bf16_tof((unsigned short)(u & 0xffff));
      } else v = 0.f;
      if (!gDP[r]) v = vold;
      unsigned short hi = bf16_rne(v);
      unsigned short lo = bf16_rne(v - bf16_tof(hi));
      hh[r][tid] = hi; hl[r][tid] = lo;
      if (hout) hout[((size_t)tl * BSZ + b0 + r) * KD + tid] = ((unsigned int)hi << 16) | lo;
      if (dout && (c0 + tl) == LSEQ - 1) dout[(size_t)(b0 + r) * KD + tid] = v;
    }
    __syncthreads();
  }

  // persist state
#pragma unroll
  for (int r = 0; r < SBR; ++r)
    hstate[(size_t)(b0 + r) * KD + tid] = ((unsigned int)hh[r][tid] << 16) | hl[r][tid];
  if (tid < SBR) { aTbuf[b0 + tid] = sAT[tid]; dTbuf[b0 + tid] = sDT[tid]; }
}

// ---------------- host ----------------
extern "C" void kernel_launch(void* const* d_in, const int* in_sizes, int n_in,
                              void* d_out, int out_size, void* d_ws, size_t ws_size,
                              hipStream_t stream)
{
  (void)in_sizes; (void)n_in; (void)out_size;
  const float* x    = (const float*)d_in[0];
  const int*   mask = (const int*)d_in[2];
  const float* Wemb = (const float*)d_in[3];
  const float* bemb = (const float*)d_in[4];
  const float* Wm   = (const float*)d_in[5];
  const float* Um   = (const float*)d_in[6];
  const float* bm   = (const float*)d_in[7];
  const float* Wa1  = (const float*)d_in[8];
  const float* Ua1  = (const float*)d_in[9];
  const float* ba1  = (const float*)d_in[10];
  const float* Wa2  = (const float*)d_in[11];
  const float* ba2  = (const float*)d_in[12];
  float* out = (float*)d_out;

  // pick chunk length CH so everything fits in ws_size
  const size_t FIXED = (size_t)16 << 20;
  const size_t PER_CH = 5ull * 1048576ull + 1310720ull; // xe + 4 ring slots + XP
  int CH = 4;
  {
    const int cands[5] = {128, 64, 32, 16, 8};
    for (int i = 0; i < 5; ++i)
      if (FIXED + (size_t)cands[i] * PER_CH <= ws_size) { CH = cands[i]; break; }
  }
  const int NCH = LSEQ / CH;

  char* p = (char*)d_ws;
  auto alloc = [&](size_t bytes) { char* r = p; p += (bytes + 255) & ~(size_t)255; return r; };

  float* Ucat  = (float*)alloc((size_t)KD * NC * 4);
  float* Wcat  = (float*)alloc((size_t)KD * NC * 4);
  float* Wcomb = (float*)alloc((size_t)KD * NC * 4);
  float* bias1 = (float*)alloc(N1 * 4);
  float* bias2 = (float*)alloc(NC * 4);
  unsigned short* BT1h = (unsigned short*)alloc((size_t)N1 * KD * 2);
  unsigned short* BT1l = (unsigned short*)alloc((size_t)N1 * KD * 2);
  unsigned short* BT2h = (unsigned short*)alloc((size_t)NC * KD * 2);
  unsigned short* BT2l = (unsigned short*)alloc((size_t)NC * KD * 2);
  unsigned short* UTh  = (unsigned short*)alloc((size_t)NC * KD * 2);
  unsigned short* UTl  = (unsigned short*)alloc((size_t)NC * KD * 2);
  int* acts0 = (int*)alloc((size_t)LSEQ * BSZ * 4);
  int* ndms0 = (int*)alloc((size_t)LSEQ * BSZ * 4);
  int* acts1 = (int*)alloc((size_t)LSEQ * BSZ * 4);
  int* ndms1 = (int*)alloc((size_t)LSEQ * BSZ * 4);
  unsigned int* hst0 = (unsigned int*)alloc((size_t)BSZ * KD * 4);
  unsigned int* hst1 = (unsigned int*)alloc((size_t)BSZ * KD * 4);
  unsigned int* hst2 = (unsigned int*)alloc((size_t)BSZ * KD * 4);
  int* aT0 = (int*)alloc(BSZ * 4); int* dT0 = (int*)alloc(BSZ * 4);
  int* aT1 = (int*)alloc(BSZ * 4); int* dT1 = (int*)alloc(BSZ * 4);
  int* aT2 = (int*)alloc(BSZ * 4); int* dT2 = (int*)alloc(BSZ * 4);
  const size_t CHUNK_ELEMS = (size_t)CH * BSZ * KD;
  unsigned int* xe_p = (unsigned int*)alloc(CHUNK_ELEMS * 4);
  unsigned int* h0r[2] = { (unsigned int*)alloc(CHUNK_ELEMS * 4), (unsigned int*)alloc(CHUNK_ELEMS * 4) };
  unsigned int* h1r[2] = { (unsigned int*)alloc(CHUNK_ELEMS * 4), (unsigned int*)alloc(CHUNK_ELEMS * 4) };
  float* XPc = (float*)alloc((size_t)CH * BSZ * NC * 4);

  // prep
  concat_k<<<(KD * NC + 255) / 256, 256, 0, stream>>>(Um, Ua1, Wm, Wa1, bm, ba1, Ucat, Wcat, bias2);
  comb_k<<<KD, NC, 0, stream>>>(Wemb, Wcat, Wcomb);
  bcomb_k<<<1, NC, 0, stream>>>(bemb, Wcat, bias2, bias1);
  tsplit_k<<<dim3(16, 16), 256, 0, stream>>>(Wemb, HH, BT1h, BT1l, 0);
  tsplit_k<<<dim3(16, 20), 256, 0, stream>>>(Wcomb, NC, BT1h, BT1l, HH);
  tsplit_k<<<dim3(16, 20), 256, 0, stream>>>(Wcat, NC, BT2h, BT2l, 0);
  tsplit_k<<<dim3(16, 20), 256, 0, stream>>>(Ucat, NC, UTh, UTl, 0);

  // lag-1 chunk pipeline: per super-step s run (L0,s), (L1,s-1), (L2,s-2)
  for (int s = 0; s < NCH + 2; ++s) {
    if (s < NCH) {
      int c = s;
      gemm_k<0, 1><<<CH * 36, 256, 0, stream>>>(x, nullptr, BT1h, BT1l, bias1, 9, c * CH, xe_p, XPc);
      scan2_k<<<BSZ / SBR, 512, 0, stream>>>(xe_p, XPc, UTh, UTl, Wa2, ba2, mask,
          nullptr, nullptr, acts0, ndms0, h0r[c & 1], hst0, aT0, dT0,
          nullptr, 0, c * CH, CH, c == 0);
    }
    if (s >= 1 && s - 1 < NCH) {
      int c = s - 1;
      gemm_k<1, 2><<<CH * 20, 256, 0, stream>>>(nullptr, h0r[c & 1], BT2h, BT2l, bias2, 5, 0, nullptr, XPc);
      scan2_k<<<BSZ / SBR, 512, 0, stream>>>(h0r[c & 1], XPc, UTh, UTl, Wa2, ba2, mask,
          acts0, ndms0, acts1, ndms1, h1r[c & 1], hst1, aT1, dT1,
          nullptr, 0, c * CH, CH, c == 0);
    }
    if (s >= 2 && s - 2 < NCH) {
      int c = s - 2;
      gemm_k<1, 2><<<CH * 20, 256, 0, stream>>>(nullptr, h1r[c & 1], BT2h, BT2l, bias2, 5, 0, nullptr, XPc);
      scan2_k<<<BSZ / SBR, 512, 0, stream>>>(h1r[c & 1], XPc, UTh, UTl, Wa2, ba2, mask,
          acts1, ndms1, nullptr, nullptr, nullptr, hst2, aT2, dT2,
          out, 1, c * CH, CH, c == 0);
    }
  }
}